// Round 9
// baseline (217.322 us; speedup 1.0000x reference)
//
#include <hip/hip_runtime.h>
#include <hip/hip_cooperative_groups.h>
#include <math.h>

namespace cg = cooperative_groups;

// Problem constants
#define BB    4
#define CIN   256
#define HH    64
#define WWID  64
#define COUT  256
#define KKS   3
#define K2    9
#define PADV  1
#define HWSZ  4096
#define GROUPS 32
#define CPG   8
#define EPSV  1e-5f
#define NKC   36            // K chunks of 64

typedef __attribute__((ext_vector_type(8))) short bf16x8;
typedef __attribute__((ext_vector_type(4))) float f32x4;
typedef __attribute__((ext_vector_type(2))) float f32x2;

__device__ __forceinline__ unsigned short f2bf(float f) {
    unsigned u = __float_as_uint(f);
    u = (u + 0x7fffu + ((u >> 16) & 1u)) >> 16;   // RNE
    return (unsigned short)u;
}
__device__ __forceinline__ f32x2 up2(unsigned q) {
    f32x2 v;
    v.x = __uint_as_float(q << 16);
    v.y = __uint_as_float(q & 0xffff0000u);
    return v;
}
__device__ __forceinline__ unsigned cvtpk(f32x2 f) {
    unsigned r;
    asm("v_cvt_pk_bf16_f32 %0, %1, %2" : "=v"(r) : "v"(f.x), "v"(f.y));
    return r;
}

// ---------------------------------------------------------------------------
// k_pre: grid (65, 8, 4).
//  bx<64 : x NCHW -> NHWC bf16 transpose, 32c x 64hw tiles
//  bx==64: weight [Cout][Cin][K2] -> FRAGMENT-major wtb:
//          byte addr = ((co>>4)*36 + kc)*2048 + ks*1024 + (hf*16 + (co&15))*16
//          so one MFMA A-fragment (lane l reads bytes l*16..l*16+15) is a
//          single 1KB contiguous, fully-coalesced global_load_dwordx4.
//          block (64,0,0) zeroes gstat.
// ---------------------------------------------------------------------------
__global__ __launch_bounds__(256)
void k_pre(const float* __restrict__ x, unsigned short* __restrict__ xh,
           const float* __restrict__ w, unsigned short* __restrict__ wtb,
           float* __restrict__ gstat) {
    int t = threadIdx.x;
    if (blockIdx.x < 64) {
        __shared__ float tile[32][65];
        int hw0 = blockIdx.x * 64;
        int c0  = blockIdx.y * 32;
        int b   = blockIdx.z;
        const float* xp = x + (size_t)b * CIN * HWSZ;
        int col = t & 63, r0 = t >> 6;
        #pragma unroll
        for (int i = 0; i < 8; i++)
            tile[i * 4 + r0][col] = xp[(c0 + i * 4 + r0) * HWSZ + hw0 + col];
        __syncthreads();
        int hw = t >> 2, cq = t & 3;
        union { unsigned short s[8]; uint4 qq; } pk;
        #pragma unroll
        for (int k = 0; k < 8; k++) pk.s[k] = f2bf(tile[cq * 8 + k][hw]);
        *(uint4*)((char*)xh + (((size_t)b * HWSZ + hw0 + hw) * CIN + c0 + cq * 8) * 2) = pk.qq;
    } else {
        if (blockIdx.y == 0 && blockIdx.z == 0)
            for (int i = t; i < BB * GROUPS * 2 + 8; i += 256) gstat[i] = 0.f;
        int idx = (blockIdx.y * 4 + blockIdx.z) * 256 + t;   // [0,8192)
        int co = idx >> 5, c8 = idx & 31;
        int q  = c8 >> 3;                // 64-ch chunk within 256
        int ks = (c8 & 7) >> 2;          // K-half within 64-chunk
        int hf = c8 & 3;                 // 8-ch slice within 32
        int lane16 = hf * 16 + (co & 15);
        for (int k2 = 0; k2 < K2; k2++) {
            int kc = k2 * 4 + q;
            union { unsigned short s[8]; uint4 qq; } pk;
            #pragma unroll
            for (int j = 0; j < 8; j++)
                pk.s[j] = f2bf(w[(co * CIN + c8 * 8 + j) * K2 + k2]);
            size_t phys = (size_t)(((co >> 4) * 36 + kc)) * 2048 + ks * 1024 + lane16 * 16;
            *(uint4*)((char*)wtb + phys) = pk.qq;
        }
    }
}

// ---------------------------------------------------------------------------
// k_conv: fused-sampling implicit GEMM + FUSED GroupNorm/ReLU (cooperative).
// K-loop byte-identical to r6 (43.6 µs, proven): 256 blocks x 512 thr
// (1 block/CU), M=256 x N=64, K=2304 in 36x64, wave grid 8m x 1n.
// A fragments read ONCE per CU (32 KB/step) straight to regs; gathers 32 KB
// (minimal). All VMEM register-destined -> counted vmcnt; per-step barrier
// lgkmcnt-only.
// Epilogue: stats atomics -> threadfence -> cg::grid::sync() (cooperative
// launch: co-residency validated by the API, no manual spin) -> in-reg
// normalize+ReLU -> single out store. Kills k_gnfinal (33.6 MB traffic +
// dispatch gap).
// ---------------------------------------------------------------------------
#define GATHER2(garr, gwarr, kn) do { \
    int k2n_ = (kn) >> 2, qn_ = (kn) & 3; \
    int cb_ = (px0 * K2 + k2n_) * 4; \
    int4   ci_ = *(const int4*)&cidx[cb_]; \
    float4 cw_ = *(const float4*)&cwgt[cb_]; \
    gwarr[0] = cw_.x; gwarr[1] = cw_.y; gwarr[2] = cw_.z; gwarr[3] = cw_.w; \
    const char* xq_ = xb + qn_ * 128; \
    garr[0] = *(const uint4*)(xq_ + ci_.x); \
    garr[1] = *(const uint4*)(xq_ + ci_.y); \
    garr[2] = *(const uint4*)(xq_ + ci_.z); \
    garr[3] = *(const uint4*)(xq_ + ci_.w); \
} while (0)

#define ISSUE_A(Ar) do { \
    Ar[0] = *(const bf16x8*)(ap0);        Ar[1] = *(const bf16x8*)(ap0 + 1024); \
    Ar[2] = *(const bf16x8*)(ap1);        Ar[3] = *(const bf16x8*)(ap1 + 1024); \
    ap0 += 2048; ap1 += 2048; \
} while (0)

#define PACK(garr, gwarr, Bdst) do { \
    f32x2 f0 = {0.f, 0.f}, f1 = {0.f, 0.f}, f2 = {0.f, 0.f}, f3 = {0.f, 0.f}; \
    _Pragma("unroll") \
    for (int c_ = 0; c_ < 4; c_++) { \
        f32x2 wv_ = { gwarr[c_], gwarr[c_] }; \
        f0 = __builtin_elementwise_fma(wv_, up2(garr[c_].x), f0); \
        f1 = __builtin_elementwise_fma(wv_, up2(garr[c_].y), f1); \
        f2 = __builtin_elementwise_fma(wv_, up2(garr[c_].z), f2); \
        f3 = __builtin_elementwise_fma(wv_, up2(garr[c_].w), f3); \
    } \
    uint4 pk_; \
    pk_.x = cvtpk(f0); pk_.y = cvtpk(f1); pk_.z = cvtpk(f2); pk_.w = cvtpk(f3); \
    *(uint4*)&(Bdst)[bofs0] = pk_; \
} while (0)

#define MFMA_STEP(Ar, Bc) do { \
    __builtin_amdgcn_s_setprio(1); \
    _Pragma("unroll") \
    for (int ks_ = 0; ks_ < 2; ks_++) { \
        int up_ = ((ks_ * 4 + hf) ^ skey) * 8; \
        bf16x8 bv_[4]; \
        _Pragma("unroll") \
        for (int ni_ = 0; ni_ < 4; ni_++) \
            bv_[ni_] = *(const bf16x8*)&(Bc)[(ni_ * 16 + r16) * 64 + up_]; \
        _Pragma("unroll") \
        for (int mi_ = 0; mi_ < 2; mi_++) \
            _Pragma("unroll") \
            for (int ni_ = 0; ni_ < 4; ni_++) \
                acc[mi_][ni_] = __builtin_amdgcn_mfma_f32_16x16x32_bf16( \
                    Ar[mi_ * 2 + ks_], bv_[ni_], acc[mi_][ni_], 0, 0, 0); \
    } \
    __builtin_amdgcn_s_setprio(0); \
} while (0)

// lgkm-only barrier: Bs ds_writes drained; in-flight VMEM (A regs, gathers)
// keeps flying across it. sched_barrier pins placement (rule #18).
#define LGKM_BAR() do { \
    asm volatile("s_waitcnt lgkmcnt(0)\n\ts_barrier" ::: "memory"); \
    __builtin_amdgcn_sched_barrier(0); \
} while (0)

#define BODY(kc, Acur, Anxt, Bcur, Bnxt, gU, gwU, gF, gwF) do { \
    ISSUE_A(Anxt); \
    GATHER2(gF, gwF, (kc) + 2); \
    __builtin_amdgcn_sched_barrier(0); \
    MFMA_STEP(Acur, Bcur); \
    __builtin_amdgcn_sched_barrier(0); \
    PACK(gU, gwU, Bnxt); \
    LGKM_BAR(); \
} while (0)

__global__ __launch_bounds__(512, 2)
void k_conv(const unsigned short* __restrict__ wtb, const unsigned short* __restrict__ xh,
            const float* __restrict__ offset, const float* __restrict__ mask,
            const float* __restrict__ bias, float* __restrict__ out,
            const float* __restrict__ gamma, const float* __restrict__ beta,
            float* __restrict__ gstat) {
    __shared__ __align__(16) unsigned short Bs[2][64 * 64];    // 16 KB
    __shared__ __align__(16) int   cidx[64 * K2 * 4];          // 9 KB (byte offsets)
    __shared__ __align__(16) float cwgt[64 * K2 * 4];          // 9 KB
    __shared__ float gs[32], gss[32];

    cg::grid_group grid = cg::this_grid();

    // block decode: XCD k = bid&7 owns strips k*32..k*32+31 (contiguous hw)
    int lid = blockIdx.x;
    int strip = (lid & 7) * 32 + (lid >> 3);   // 0..255
    int b = strip >> 6;
    int hwbase = (strip & 63) * 64;

    int t = threadIdx.x, w = t >> 6, l = t & 63;
    int r16 = l & 15, hf = l >> 4;
    int skey = r16 & 7;

    if (t < 32) { gs[t] = 0.f; gss[t] = 0.f; }

    // ---- corner prep: 576 (px,k2) pairs
    for (int i = t; i < 64 * K2; i += 512) {
        int px = i / K2, k2 = i - px * K2;
        int hw = hwbase + px;
        int ho = hw >> 6, wo = hw & 63;
        int ky = k2 / KKS, kx = k2 - ky * KKS;
        float dy = offset[((b * (2 * K2) + k2 * 2 + 0) * HWSZ) + hw];
        float dx = offset[((b * (2 * K2) + k2 * 2 + 1) * HWSZ) + hw];
        float m  = mask[(b * K2 + k2) * HWSZ + hw];
        float y  = (float)(ky + ho - PADV) + dy;
        float xc = (float)(kx + wo - PADV) + dx;
        float y0f = floorf(y), x0f = floorf(xc);
        float fy = y - y0f, fx = xc - x0f;
        int y0 = (int)y0f, x0 = (int)x0f;
        int   yy[2] = { y0, y0 + 1 };
        int   xx[2] = { x0, x0 + 1 };
        float wy[2] = { 1.f - fy, fy };
        float wx[2] = { 1.f - fx, fx };
        #pragma unroll
        for (int ii = 0; ii < 2; ii++)
            #pragma unroll
            for (int jj = 0; jj < 2; jj++) {
                int yi = yy[ii], xi = xx[jj];
                bool valid = (yi >= 0) && (yi < HH) && (xi >= 0) && (xi < WWID);
                int yc  = min(max(yi, 0), HH - 1);
                int xcc = min(max(xi, 0), WWID - 1);
                cidx[i * 4 + ii * 2 + jj] = (yc * WWID + xcc) << 9;   // byte offset
                cwgt[i * 4 + ii * 2 + jj] = valid ? (wy[ii] * wx[jj] * m) : 0.f;
            }
    }

    // ---- A fragment pointers: wave w owns co-tiles w*2, w*2+1; +2KB per kc
    const char* wb = (const char*)wtb + (size_t)l * 16;
    const char* ap0 = wb + (size_t)((w * 2 + 0) * 36) * 2048;
    const char* ap1 = wb + (size_t)((w * 2 + 1) * 36) * 2048;

    // ---- sampling mapping: 1 item/thread: px = t>>3 (0..63), sc = t&7
    int sc  = t & 7;
    int px0 = t >> 3;
    const char* xb = (const char*)xh + (size_t)b * HWSZ * CIN * 2 + sc * 16;
    int bofs0 = px0 * 64 + (sc ^ (px0 & 7)) * 8;

    f32x4 acc[2][4];
    #pragma unroll
    for (int mi = 0; mi < 2; mi++)
        #pragma unroll
        for (int ni = 0; ni < 4; ni++) acc[mi][ni] = (f32x4)0.f;

    __syncthreads();   // coef + gs ready

    // ---- prologue
    uint4 gA[4], gB[4]; float gwA[4], gwB[4];
    bf16x8 Aa[4], Ab[4];
    GATHER2(gA, gwA, 0);
    ISSUE_A(Aa);              // A(0)
    GATHER2(gB, gwB, 1);
    PACK(gA, gwA, Bs[0]);     // B(0); waits its gathers (counted), A in flight
    LGKM_BAR();

    unsigned short* Bs0 = &Bs[0][0];
    unsigned short* Bs1 = &Bs[1][0];

    // ---- main loop: bodies 0..33 (2-unrolled), then body 34, tail 35
    for (int kc2 = 0; kc2 < 34; kc2 += 2) {
        BODY(kc2,     Aa, Ab, Bs0, Bs1, gB, gwB, gA, gwA);
        BODY(kc2 + 1, Ab, Aa, Bs1, Bs0, gA, gwA, gB, gwB);
    }
    // body 34: issue A(35), MFMA(34), pack B(35) from gB; no gather fill
    ISSUE_A(Ab);
    __builtin_amdgcn_sched_barrier(0);
    MFMA_STEP(Aa, Bs0);
    __builtin_amdgcn_sched_barrier(0);
    PACK(gB, gwB, Bs1);
    LGKM_BAR();
    // tail: kc=35
    MFMA_STEP(Ab, Bs1);

    // ---- stats (no store yet): v = acc + bias
    int gb = hf >> 1;
    float s4[2] = {0,0}, ss4[2] = {0,0};
    #pragma unroll
    for (int mi = 0; mi < 2; mi++) {
        #pragma unroll
        for (int r = 0; r < 4; r++) {
            int co = w * 32 + mi * 16 + hf * 4 + r;
            float bs = bias[co];
            #pragma unroll
            for (int ni = 0; ni < 4; ni++) {
                float v = acc[mi][ni][r] + bs;
                s4[mi] += v; ss4[mi] += v * v;
            }
        }
    }
    #pragma unroll
    for (int mi = 0; mi < 2; mi++) {
        atomicAdd(&gs [w * 4 + mi * 2 + gb], s4[mi]);
        atomicAdd(&gss[w * 4 + mi * 2 + gb], ss4[mi]);
    }
    __syncthreads();
    if (t < 32) {
        atomicAdd(&gstat[(b * GROUPS + t) * 2 + 0], gs[t]);
        atomicAdd(&gstat[(b * GROUPS + t) * 2 + 1], gss[t]);
    }

    // ---- grid-wide sync (cooperative launch; co-residency validated by API)
    __threadfence();
    grid.sync();

    // ---- in-reg normalize + ReLU + single store
    const float inv = 1.f / (float)(CPG * HWSZ);
    #pragma unroll
    for (int mi = 0; mi < 2; mi++) {
        int gidx = (b * GROUPS + w * 4 + mi * 2 + gb) * 2;
        float s  = __hip_atomic_load(&gstat[gidx + 0], __ATOMIC_RELAXED, __HIP_MEMORY_SCOPE_AGENT);
        float ss = __hip_atomic_load(&gstat[gidx + 1], __ATOMIC_RELAXED, __HIP_MEMORY_SCOPE_AGENT);
        float mu  = s * inv;
        float var = ss * inv - mu * mu;
        float rstd = rsqrtf(var + EPSV);
        #pragma unroll
        for (int r = 0; r < 4; r++) {
            int co = w * 32 + mi * 16 + hf * 4 + r;
            float bs = bias[co];
            float ga = gamma[co] * rstd;
            float be = beta[co] - mu * ga;
            float* orow = out + ((size_t)(b * COUT + co)) * HWSZ;
            #pragma unroll
            for (int ni = 0; ni < 4; ni++) {
                int n = hwbase + ni * 16 + r16;
                float v = acc[mi][ni][r] + bs;
                orow[n] = fmaxf(v * ga + be, 0.f);
            }
        }
    }
}

// ---------------------------------------------------------------------------
extern "C" void kernel_launch(void* const* d_in, const int* in_sizes, int n_in,
                              void* d_out, int out_size, void* d_ws, size_t ws_size,
                              hipStream_t stream) {
    const float* x      = (const float*)d_in[0];
    const float* offset = (const float*)d_in[1];
    const float* mask   = (const float*)d_in[2];
    const float* weight = (const float*)d_in[3];
    const float* bias   = (const float*)d_in[4];
    const float* gamma  = (const float*)d_in[5];
    const float* beta   = (const float*)d_in[6];
    float* out = (float*)d_out;

    // workspace (~10 MB)
    unsigned short* xh    = (unsigned short*)d_ws;              // 4,194,304 us (8.4 MB)
    unsigned short* wtb   = xh + (size_t)4194304;               //   589,824 us (1.2 MB)
    float*          gstat = (float*)(wtb + (size_t)589824);     // 264 f

    k_pre<<<dim3(65, 8, 4), 256, 0, stream>>>(x, xh, weight, wtb, gstat);

    void* params[] = { (void*)&wtb, (void*)&xh, (void*)&offset, (void*)&mask,
                       (void*)&bias, (void*)&out, (void*)&gamma, (void*)&beta,
                       (void*)&gstat };
    hipLaunchCooperativeKernel(reinterpret_cast<void*>(k_conv),
                               dim3(256), dim3(512), params, 0, stream);
}

// Round 10
// 133.832 us; speedup vs baseline: 1.6238x; 1.6238x over previous
//
#include <hip/hip_runtime.h>
#include <math.h>

// Problem constants
#define BB    4
#define CIN   256
#define HH    64
#define WWID  64
#define COUT  256
#define KKS   3
#define K2    9
#define PADV  1
#define HWSZ  4096
#define GROUPS 32
#define CPG   8
#define EPSV  1e-5f
#define NKC   36            // K chunks of 64

typedef __attribute__((ext_vector_type(8))) short bf16x8;
typedef __attribute__((ext_vector_type(4))) float f32x4;
typedef __attribute__((ext_vector_type(2))) float f32x2;

__device__ __forceinline__ unsigned short f2bf(float f) {
    unsigned u = __float_as_uint(f);
    u = (u + 0x7fffu + ((u >> 16) & 1u)) >> 16;   // RNE
    return (unsigned short)u;
}
__device__ __forceinline__ f32x2 up2(unsigned q) {
    f32x2 v;
    v.x = __uint_as_float(q << 16);
    v.y = __uint_as_float(q & 0xffff0000u);
    return v;
}
__device__ __forceinline__ unsigned cvtpk(f32x2 f) {
    unsigned r;
    asm("v_cvt_pk_bf16_f32 %0, %1, %2" : "=v"(r) : "v"(f.x), "v"(f.y));
    return r;
}

// ---------------------------------------------------------------------------
// k_pre: grid (65, 8, 4).
//  bx<64 : x NCHW -> NHWC bf16 transpose, 32c x 64hw tiles
//  bx==64: weight [Cout][Cin][K2] -> FRAGMENT-major wtb:
//          byte addr = ((co>>4)*36 + kc)*2048 + ks*1024 + (hf*16 + (co&15))*16
//          so one MFMA A-fragment (lane l reads bytes l*16..l*16+15) is a
//          single 1KB contiguous, fully-coalesced global_load_dwordx4.
//          block (64,0,0) zeroes gstat.
// ---------------------------------------------------------------------------
__global__ __launch_bounds__(256)
void k_pre(const float* __restrict__ x, unsigned short* __restrict__ xh,
           const float* __restrict__ w, unsigned short* __restrict__ wtb,
           float* __restrict__ gstat) {
    int t = threadIdx.x;
    if (blockIdx.x < 64) {
        __shared__ float tile[32][65];
        int hw0 = blockIdx.x * 64;
        int c0  = blockIdx.y * 32;
        int b   = blockIdx.z;
        const float* xp = x + (size_t)b * CIN * HWSZ;
        int col = t & 63, r0 = t >> 6;
        #pragma unroll
        for (int i = 0; i < 8; i++)
            tile[i * 4 + r0][col] = xp[(c0 + i * 4 + r0) * HWSZ + hw0 + col];
        __syncthreads();
        int hw = t >> 2, cq = t & 3;
        union { unsigned short s[8]; uint4 qq; } pk;
        #pragma unroll
        for (int k = 0; k < 8; k++) pk.s[k] = f2bf(tile[cq * 8 + k][hw]);
        *(uint4*)((char*)xh + (((size_t)b * HWSZ + hw0 + hw) * CIN + c0 + cq * 8) * 2) = pk.qq;
    } else {
        if (blockIdx.y == 0 && blockIdx.z == 0)
            for (int i = t; i < BB * GROUPS * 2 + 8; i += 256) gstat[i] = 0.f;
        int idx = (blockIdx.y * 4 + blockIdx.z) * 256 + t;   // [0,8192)
        int co = idx >> 5, c8 = idx & 31;
        int q  = c8 >> 3;                // 64-ch chunk within 256
        int ks = (c8 & 7) >> 2;          // K-half within 64-chunk
        int hf = c8 & 3;                 // 8-ch slice within 32
        int lane16 = hf * 16 + (co & 15);
        for (int k2 = 0; k2 < K2; k2++) {
            int kc = k2 * 4 + q;
            union { unsigned short s[8]; uint4 qq; } pk;
            #pragma unroll
            for (int j = 0; j < 8; j++)
                pk.s[j] = f2bf(w[(co * CIN + c8 * 8 + j) * K2 + k2]);
            size_t phys = (size_t)(((co >> 4) * 36 + kc)) * 2048 + ks * 1024 + lane16 * 16;
            *(uint4*)((char*)wtb + phys) = pk.qq;
        }
    }
}

// ---------------------------------------------------------------------------
// k_conv: fused-sampling implicit GEMM — VMEM-traffic-minimal tiling (r6).
// 256 blocks x 512 thr (1 block/CU). M=256 x N=64, K=2304 in 36x64.
// Wave grid 8m x 1n: wave w owns C rows w*32..w*32+31, all 64 px ->
// every A fragment read ONCE per CU per step: A = 32 KB/CU/step,
// gathers 32 KB -> 64 KB/CU/step total (both operand streams byte-minimal;
// r4/r5 at 96 KB both ran 57.4 µs -> VMEM-throughput-bound, traffic scaling
// confirmed by r6's -24%; TLP null r5; BK=128 null r8; NT regression r7).
// A: fragment-major wtb straight to regs (4 x 1KB coalesced loads/wave/step),
//    register double-buffered one step ahead.
// B: every thread gathers+packs 1 item (64 px x 8 sc), 2-deep prefetch,
//    v_pk_fma + cvt_pk_bf16, Bs LDS double-buffered.
// ALL VMEM register-destined -> counted vmcnt; per-step barrier is
// lgkmcnt-only — vmcnt never drained in-loop.
// ---------------------------------------------------------------------------
#define GATHER2(garr, gwarr, kn) do { \
    int k2n_ = (kn) >> 2, qn_ = (kn) & 3; \
    int cb_ = (px0 * K2 + k2n_) * 4; \
    int4   ci_ = *(const int4*)&cidx[cb_]; \
    float4 cw_ = *(const float4*)&cwgt[cb_]; \
    gwarr[0] = cw_.x; gwarr[1] = cw_.y; gwarr[2] = cw_.z; gwarr[3] = cw_.w; \
    const char* xq_ = xb + qn_ * 128; \
    garr[0] = *(const uint4*)(xq_ + ci_.x); \
    garr[1] = *(const uint4*)(xq_ + ci_.y); \
    garr[2] = *(const uint4*)(xq_ + ci_.z); \
    garr[3] = *(const uint4*)(xq_ + ci_.w); \
} while (0)

#define ISSUE_A(Ar) do { \
    Ar[0] = *(const bf16x8*)(ap0);        Ar[1] = *(const bf16x8*)(ap0 + 1024); \
    Ar[2] = *(const bf16x8*)(ap1);        Ar[3] = *(const bf16x8*)(ap1 + 1024); \
    ap0 += 2048; ap1 += 2048; \
} while (0)

#define PACK(garr, gwarr, Bdst) do { \
    f32x2 f0 = {0.f, 0.f}, f1 = {0.f, 0.f}, f2 = {0.f, 0.f}, f3 = {0.f, 0.f}; \
    _Pragma("unroll") \
    for (int c_ = 0; c_ < 4; c_++) { \
        f32x2 wv_ = { gwarr[c_], gwarr[c_] }; \
        f0 = __builtin_elementwise_fma(wv_, up2(garr[c_].x), f0); \
        f1 = __builtin_elementwise_fma(wv_, up2(garr[c_].y), f1); \
        f2 = __builtin_elementwise_fma(wv_, up2(garr[c_].z), f2); \
        f3 = __builtin_elementwise_fma(wv_, up2(garr[c_].w), f3); \
    } \
    uint4 pk_; \
    pk_.x = cvtpk(f0); pk_.y = cvtpk(f1); pk_.z = cvtpk(f2); pk_.w = cvtpk(f3); \
    *(uint4*)&(Bdst)[bofs0] = pk_; \
} while (0)

#define MFMA_STEP(Ar, Bc) do { \
    __builtin_amdgcn_s_setprio(1); \
    _Pragma("unroll") \
    for (int ks_ = 0; ks_ < 2; ks_++) { \
        int up_ = ((ks_ * 4 + hf) ^ skey) * 8; \
        bf16x8 bv_[4]; \
        _Pragma("unroll") \
        for (int ni_ = 0; ni_ < 4; ni_++) \
            bv_[ni_] = *(const bf16x8*)&(Bc)[(ni_ * 16 + r16) * 64 + up_]; \
        _Pragma("unroll") \
        for (int mi_ = 0; mi_ < 2; mi_++) \
            _Pragma("unroll") \
            for (int ni_ = 0; ni_ < 4; ni_++) \
                acc[mi_][ni_] = __builtin_amdgcn_mfma_f32_16x16x32_bf16( \
                    Ar[mi_ * 2 + ks_], bv_[ni_], acc[mi_][ni_], 0, 0, 0); \
    } \
    __builtin_amdgcn_s_setprio(0); \
} while (0)

// lgkm-only barrier: Bs ds_writes drained; in-flight VMEM (A regs, gathers)
// keeps flying across it. sched_barrier pins placement (rule #18).
#define LGKM_BAR() do { \
    asm volatile("s_waitcnt lgkmcnt(0)\n\ts_barrier" ::: "memory"); \
    __builtin_amdgcn_sched_barrier(0); \
} while (0)

#define BODY(kc, Acur, Anxt, Bcur, Bnxt, gU, gwU, gF, gwF) do { \
    ISSUE_A(Anxt); \
    GATHER2(gF, gwF, (kc) + 2); \
    __builtin_amdgcn_sched_barrier(0); \
    MFMA_STEP(Acur, Bcur); \
    __builtin_amdgcn_sched_barrier(0); \
    PACK(gU, gwU, Bnxt); \
    LGKM_BAR(); \
} while (0)

__global__ __launch_bounds__(512, 2)
void k_conv(const unsigned short* __restrict__ wtb, const unsigned short* __restrict__ xh,
            const float* __restrict__ offset, const float* __restrict__ mask,
            const float* __restrict__ bias, float* __restrict__ out,
            float* __restrict__ gstat) {
    __shared__ __align__(16) unsigned short Bs[2][64 * 64];    // 16 KB
    __shared__ __align__(16) int   cidx[64 * K2 * 4];          // 9 KB (byte offsets)
    __shared__ __align__(16) float cwgt[64 * K2 * 4];          // 9 KB
    __shared__ float gs[32], gss[32];

    // block decode: XCD k = bid&7 owns strips k*32..k*32+31 (contiguous hw)
    int lid = blockIdx.x;
    int strip = (lid & 7) * 32 + (lid >> 3);   // 0..255
    int b = strip >> 6;
    int hwbase = (strip & 63) * 64;

    int t = threadIdx.x, w = t >> 6, l = t & 63;
    int r16 = l & 15, hf = l >> 4;
    int skey = r16 & 7;

    if (t < 32) { gs[t] = 0.f; gss[t] = 0.f; }

    // ---- corner prep: 576 (px,k2) pairs
    for (int i = t; i < 64 * K2; i += 512) {
        int px = i / K2, k2 = i - px * K2;
        int hw = hwbase + px;
        int ho = hw >> 6, wo = hw & 63;
        int ky = k2 / KKS, kx = k2 - ky * KKS;
        float dy = offset[((b * (2 * K2) + k2 * 2 + 0) * HWSZ) + hw];
        float dx = offset[((b * (2 * K2) + k2 * 2 + 1) * HWSZ) + hw];
        float m  = mask[(b * K2 + k2) * HWSZ + hw];
        float y  = (float)(ky + ho - PADV) + dy;
        float xc = (float)(kx + wo - PADV) + dx;
        float y0f = floorf(y), x0f = floorf(xc);
        float fy = y - y0f, fx = xc - x0f;
        int y0 = (int)y0f, x0 = (int)x0f;
        int   yy[2] = { y0, y0 + 1 };
        int   xx[2] = { x0, x0 + 1 };
        float wy[2] = { 1.f - fy, fy };
        float wx[2] = { 1.f - fx, fx };
        #pragma unroll
        for (int ii = 0; ii < 2; ii++)
            #pragma unroll
            for (int jj = 0; jj < 2; jj++) {
                int yi = yy[ii], xi = xx[jj];
                bool valid = (yi >= 0) && (yi < HH) && (xi >= 0) && (xi < WWID);
                int yc  = min(max(yi, 0), HH - 1);
                int xcc = min(max(xi, 0), WWID - 1);
                cidx[i * 4 + ii * 2 + jj] = (yc * WWID + xcc) << 9;   // byte offset
                cwgt[i * 4 + ii * 2 + jj] = valid ? (wy[ii] * wx[jj] * m) : 0.f;
            }
    }

    // ---- A fragment pointers: wave w owns co-tiles w*2, w*2+1; +2KB per kc
    const char* wb = (const char*)wtb + (size_t)l * 16;
    const char* ap0 = wb + (size_t)((w * 2 + 0) * 36) * 2048;
    const char* ap1 = wb + (size_t)((w * 2 + 1) * 36) * 2048;

    // ---- sampling mapping: 1 item/thread: px = t>>3 (0..63), sc = t&7
    int sc  = t & 7;
    int px0 = t >> 3;
    const char* xb = (const char*)xh + (size_t)b * HWSZ * CIN * 2 + sc * 16;
    int bofs0 = px0 * 64 + (sc ^ (px0 & 7)) * 8;

    f32x4 acc[2][4];
    #pragma unroll
    for (int mi = 0; mi < 2; mi++)
        #pragma unroll
        for (int ni = 0; ni < 4; ni++) acc[mi][ni] = (f32x4)0.f;

    __syncthreads();   // coef + gs ready

    // ---- prologue
    uint4 gA[4], gB[4]; float gwA[4], gwB[4];
    bf16x8 Aa[4], Ab[4];
    GATHER2(gA, gwA, 0);
    ISSUE_A(Aa);              // A(0)
    GATHER2(gB, gwB, 1);
    PACK(gA, gwA, Bs[0]);     // B(0); waits its gathers (counted), A in flight
    LGKM_BAR();

    unsigned short* Bs0 = &Bs[0][0];
    unsigned short* Bs1 = &Bs[1][0];

    // ---- main loop: bodies 0..33 (2-unrolled), then body 34, tail 35
    for (int kc2 = 0; kc2 < 34; kc2 += 2) {
        BODY(kc2,     Aa, Ab, Bs0, Bs1, gB, gwB, gA, gwA);
        BODY(kc2 + 1, Ab, Aa, Bs1, Bs0, gA, gwA, gB, gwB);
    }
    // body 34: issue A(35), MFMA(34), pack B(35) from gB; no gather fill
    ISSUE_A(Ab);
    __builtin_amdgcn_sched_barrier(0);
    MFMA_STEP(Aa, Bs0);
    __builtin_amdgcn_sched_barrier(0);
    PACK(gB, gwB, Bs1);
    LGKM_BAR();
    // tail: kc=35
    MFMA_STEP(Ab, Bs1);

    // ---- epilogue: bias + store + GN partials (C/D: col=lane&15, row=hf*4+r)
    float s4[2] = {0,0}, ss4[2] = {0,0};
    #pragma unroll
    for (int mi = 0; mi < 2; mi++) {
        #pragma unroll
        for (int r = 0; r < 4; r++) {
            int co = w * 32 + mi * 16 + hf * 4 + r;
            float bs = bias[co];
            float* orow = out + ((size_t)(b * COUT + co)) * HWSZ;
            #pragma unroll
            for (int ni = 0; ni < 4; ni++) {
                int n = hwbase + ni * 16 + r16;
                float v = acc[mi][ni][r] + bs;
                orow[n] = v;
                s4[mi] += v; ss4[mi] += v * v;
            }
        }
    }
    int gb = hf >> 1;
    #pragma unroll
    for (int mi = 0; mi < 2; mi++) {
        atomicAdd(&gs [w * 4 + mi * 2 + gb], s4[mi]);
        atomicAdd(&gss[w * 4 + mi * 2 + gb], ss4[mi]);
    }
    __syncthreads();
    if (t < 32) {
        atomicAdd(&gstat[(b * GROUPS + t) * 2 + 0], gs[t]);
        atomicAdd(&gstat[(b * GROUPS + t) * 2 + 1], gss[t]);
    }
}

// ---------------------------------------------------------------------------
// finalize: normalize + affine + ReLU in place (float4)
// ---------------------------------------------------------------------------
__global__ __launch_bounds__(256)
void k_gnfinal(float* __restrict__ out, const float* __restrict__ gstat,
               const float* __restrict__ gamma, const float* __restrict__ beta) {
    int i4 = blockIdx.x * 256 + threadIdx.x;
    int e  = i4 * 4;
    int c  = (e >> 12) & 255;
    int b  = e >> 20;
    int g  = c >> 3;
    float s  = gstat[((b * GROUPS) + g) * 2 + 0];
    float ss = gstat[((b * GROUPS) + g) * 2 + 1];
    const float inv = 1.f / (float)(CPG * HWSZ);
    float mu  = s * inv;
    float var = ss * inv - mu * mu;
    float rstd = rsqrtf(var + EPSV);
    float ga = gamma[c] * rstd;
    float be = beta[c] - mu * ga;
    float4 v = ((float4*)out)[i4];
    v.x = fmaxf(v.x * ga + be, 0.f);
    v.y = fmaxf(v.y * ga + be, 0.f);
    v.z = fmaxf(v.z * ga + be, 0.f);
    v.w = fmaxf(v.w * ga + be, 0.f);
    ((float4*)out)[i4] = v;
}

// ---------------------------------------------------------------------------
extern "C" void kernel_launch(void* const* d_in, const int* in_sizes, int n_in,
                              void* d_out, int out_size, void* d_ws, size_t ws_size,
                              hipStream_t stream) {
    const float* x      = (const float*)d_in[0];
    const float* offset = (const float*)d_in[1];
    const float* mask   = (const float*)d_in[2];
    const float* weight = (const float*)d_in[3];
    const float* bias   = (const float*)d_in[4];
    const float* gamma  = (const float*)d_in[5];
    const float* beta   = (const float*)d_in[6];
    float* out = (float*)d_out;

    // workspace (~10 MB)
    unsigned short* xh    = (unsigned short*)d_ws;              // 4,194,304 us (8.4 MB)
    unsigned short* wtb   = xh + (size_t)4194304;               //   589,824 us (1.2 MB)
    float*          gstat = (float*)(wtb + (size_t)589824);     // 264 f

    k_pre<<<dim3(65, 8, 4), 256, 0, stream>>>(x, xh, weight, wtb, gstat);
    k_conv<<<256, 512, 0, stream>>>(wtb, xh, offset, mask, bias, out, gstat);
    k_gnfinal<<<(size_t)BB * COUT * HWSZ / 1024, 256, 0, stream>>>(out, gstat, gamma, beta);
}